// Round 10
// baseline (35.763 us; speedup 1.0000x reference)
//
#include <hip/hip_runtime.h>

#define BB 8
#define HH 64
#define WW 2048
#define HW (HH * WW)
#define NC 20
#define TPB 256

// R10: gate-first kernel. 4x64 tile per compute step; 2 tiles per persistent
// block, double-buffered. DEPTH ONLY staged (8 rows y0-4..y0+3 x 72 cols,
// 0.0-padded = exact reference unfold pad). Labels are never staged: fast
// path reads own label coalesced; rare slow path gathers from global.
// Gate (R9, exact): dist[k] is an fl-monotone nondecreasing chain; if after
// the jy=0 tap row (a CHAIN PREFIX) all 24 non-self dists > CUTOFF=1.0, the
// final top-5 is provably {self,NC,NC,NC,NC} -> output own label. Failing
// waves recompute everything from global in exact chain order (bit-identical).

__device__ __forceinline__ void tile_coords(int tid, int& bb, int& y0, int& x0) {
    int tx = tid & 31;          // x fastest: consecutive tiles share halo cols
    int r  = tid >> 5;
    int ty = r & 15;
    bb = r >> 4;
    y0 = ty * 4;
    x0 = tx * 64;
}

__device__ __forceinline__ void stage_load(const float* __restrict__ depth,
                                           int tid, int t, float dreg[3]) {
    int bb, y0, x0;
    tile_coords(tid, bb, y0, x0);
    const float* Db = depth + (size_t)bb * HW;
#pragma unroll
    for (int i = 0; i < 3; ++i) {
        int idx = t + i * TPB;
        float v = 0.0f;
        if (idx < 8 * 72) {
            int ry = idx / 72, rx = idx - ry * 72;
            int gy = y0 + ry - 4, gx = x0 + rx - 4;
            if ((unsigned)gy < (unsigned)HH && (unsigned)gx < (unsigned)WW)
                v = Db[gy * WW + gx];
        }
        dreg[i] = v;
    }
}

__device__ __forceinline__ void stage_write(float (*sD)[72], int t,
                                            const float dreg[3]) {
#pragma unroll
    for (int i = 0; i < 3; ++i) {
        int idx = t + i * TPB;
        if (idx < 8 * 72) (&sD[0][0])[idx] = dreg[i];
    }
}

__device__ __forceinline__ float gdepth(const float* __restrict__ Db, int y, int x) {
    // exact reference zero-pad
    return ((unsigned)y < (unsigned)HH && (unsigned)x < (unsigned)WW)
               ? Db[y * WW + x] : 0.0f;
}

__device__ __forceinline__ void compute_tile(const float (*sDt)[72],
                                             const float* sW,
                                             const float* __restrict__ depth,
                                             const int*   __restrict__ label,
                                             int tid, int t,
                                             int* __restrict__ out) {
    int bb, y0, x0;
    tile_coords(tid, bb, y0, x0);
    const int px = t & 63, py = t >> 6;
    const int gy = y0 + py, gx = x0 + px;
    const float* Db = depth + (size_t)bb * HW;
    const int*   Lb = label + (size_t)bb * HW;

    // own label: coalesced global load, issued early; labs[0] on BOTH paths
    // (k=12 has dist exactly +0.0 -> always the first top-k pick, R7 proof)
    const int labSelf = Lb[gy * WW + gx];

    // anchor-OOB masks (exact 0/1): conv zero-pads jump in p-space
    float mx[5];
#pragma unroll
    for (int d = 0; d < 5; ++d)
        mx[d] = ((unsigned)(gx + d - 2) < (unsigned)WW) ? 1.0f : 0.0f;

    float dist[25];
#pragma unroll
    for (int k = 0; k < 25; ++k) dist[k] = 0.0f;

    // ---- gate: jy=0 tap row (chain prefix -> rigorous fl lower bound) ----
    {
        const float my0 = ((unsigned)(gy - 2) < (unsigned)HH) ? 1.0f : 0.0f;
#pragma unroll
        for (int jx = 0; jx < 5; ++jx) {
            const float wj = my0 * mx[jx] * sW[jx];
            const float Dq = sDt[py + 2][px + jx + 2];
#pragma unroll
            for (int k = 0; k < 25; ++k) {
                if (k == 12) continue;
                const int ky = k / 5, kx = k % 5;
                // per-row rebased pointer, small static offsets (read2-friendly)
                const float nbv = (&sDt[py + ky][px + jx])[kx];
                const int nlin = ky * 9 + jx + kx, alin = 18 + jx + 2;
                // canonical operand order: |x-y|==|y-x| bit-exact, enables CSE
                const float diff = (nlin > alin) ? (nbv - Dq) : (Dq - nbv);
                dist[k] = fmaf(wj, fabsf(diff), dist[k]);
            }
        }
    }

    float mn = 3.4e38f;
#pragma unroll
    for (int k = 0; k < 25; ++k) {
        if (k == 12) continue;
        mn = fminf(mn, dist[k]);
    }
    int* const op = &out[(size_t)bb * HW + (size_t)gy * WW + gx];
    if (__all(mn > 1.0f)) {
        *op = labSelf;
        return;
    }

    // ---- slow path (rare, wave-uniform): full exact recompute from global,
    //      j-ascending chain order, identical padding -> bit-identical dist --
#pragma unroll
    for (int k = 0; k < 25; ++k) dist[k] = 0.0f;
#pragma clang loop unroll(disable)
    for (int jy = 0; jy < 5; ++jy) {
        float row[5][9];                       // statically indexed only
#pragma unroll
        for (int r = 0; r < 5; ++r)
#pragma unroll
            for (int c = 0; c < 9; ++c)
                row[r][c] = gdepth(Db, gy + jy + r - 4, gx + c - 4);
        const float myy = ((unsigned)(gy + jy - 2) < (unsigned)HH) ? 1.0f : 0.0f;
#pragma unroll
        for (int jx = 0; jx < 5; ++jx) {
            const float wj = myy * mx[jx] * sW[jy * 5 + jx];
            const float Dq = row[2][jx + 2];
#pragma unroll
            for (int k = 0; k < 25; ++k) {
                if (k == 12) continue;
                const int ky = k / 5, kx = k % 5;
                const int nlin = ky * 9 + jx + kx, alin = 18 + jx + 2;
                const float diff = (nlin > alin) ? (row[ky][jx + kx] - Dq)
                                                 : (Dq - row[ky][jx + kx]);
                dist[k] = fmaf(wj, fabsf(diff), dist[k]);
            }
        }
    }

    // top-5 smallest (strict <, ties -> lower k = lax.top_k); round 0 = k=12
    int labs[5];
    labs[0] = labSelf;
#pragma unroll
    for (int r = 1; r < 5; ++r) {
        float best = 3.4e38f;
        int bi = 0;
#pragma unroll
        for (int k = 0; k < 25; ++k) {
            if (k == 12) continue;
            if (dist[k] < best) { best = dist[k]; bi = k; }
        }
        int ky = (bi * 205) >> 10, kx = bi - ky * 5;
        int ny = gy + ky - 2, nx = gx + kx - 2;
        // label unfold zero-pad: OOB neighbor label = 0
        int lv = ((unsigned)ny < (unsigned)HH && (unsigned)nx < (unsigned)WW)
                     ? Lb[ny * WW + nx] : 0;
        labs[r] = (best > 1.0f) ? NC : lv;
        if (r < 4) {
#pragma unroll
            for (int k = 0; k < 25; ++k) {
                if (k == 12) continue;
                if (k == bi) dist[k] = 3.4e38f;
            }
        }
    }

    // majority vote; argmax ties -> lowest class index
    int bestLab = 0, bestCnt = 0;
#pragma unroll
    for (int i = 0; i < 5; ++i) {
        const int li = labs[i];
        int c = 0;
#pragma unroll
        for (int j = 0; j < 5; ++j) c += (labs[j] == li) ? 1 : 0;
        if (li < NC && (c > bestCnt || (c == bestCnt && li < bestLab))) {
            bestCnt = c;
            bestLab = li;
        }
    }
    *op = bestLab;
}

__global__ __launch_bounds__(TPB) void knn_refine(
    const float* __restrict__ depth,
    const int*   __restrict__ label,
    const float* __restrict__ wker,
    int*         __restrict__ out)
{
    __shared__ float sD[2][8][72];
    __shared__ float sW[25];

    const int t    = threadIdx.x;
    const int tid0 = blockIdx.x * 2;          // 2 tiles per persistent block

    float dreg[3];

    // prologue: stage tile 0 into buffer 0
    stage_load(depth, tid0, t, dreg);
    if (t < 25) sW[t] = wker[t];
    stage_write(sD[0], t, dreg);
    __syncthreads();

    // tile 0: issue tile-1 loads FIRST (hidden under compute), then compute,
    // then park loads into buffer 1.
    stage_load(depth, tid0 + 1, t, dreg);
    compute_tile(sD[0], sW, depth, label, tid0, t, out);
    stage_write(sD[1], t, dreg);
    __syncthreads();

    // tile 1
    compute_tile(sD[1], sW, depth, label, tid0 + 1, t, out);
}

extern "C" void kernel_launch(void* const* d_in, const int* in_sizes, int n_in,
                              void* d_out, int out_size, void* d_ws, size_t ws_size,
                              hipStream_t stream) {
    const float* depth = (const float*)d_in[0];
    const int*   label = (const int*)d_in[1];
    const float* wker  = (const float*)d_in[2];
    int*         out   = (int*)d_out;

    knn_refine<<<dim3(2048), dim3(TPB), 0, stream>>>(depth, label, wker, out);
}

// Round 11
// 21.883 us; speedup vs baseline: 1.6343x; 1.6343x over previous
//
#include <hip/hip_runtime.h>

#define BB 8
#define HH 64
#define WW 2048
#define HW (HH * WW)
#define NC 20
#define TPB 256

// R11: per-row-gated kernel. 4x64 tile per compute step; 2 tiles per
// persistent block, double-buffered; depth staged 12 rows x 72 (0.0-padded =
// exact reference unfold pad); labels NEVER staged (own label read coalesced,
// neighbor labels gathered globally on the ~unreachable full path).
//
// Gate (exact, monotone): dist[k] accumulates the reference's fma chain in
// j-ascending order; after EACH tap row, prefix <= final (fma w/ nonneg
// addend is monotone under round-to-nearest). If all 24 non-self prefixes
// exceed CUTOFF=1.0, final top-5 = {self,NC,NC,NC,NC} -> own label.
// R10 lesson: gating ONLY after row 0 systematically fails for gy in {0,1}
// (whole row conv-masked, prefix == 0) -> 512 waves took the slow path every
// dispatch = the tail that set kernel duration. Per-row gating exits those
// waves at row 2 (always unmasked); no separate slow path exists at all.

__device__ __forceinline__ void tile_coords(int tid, int& bb, int& y0, int& x0) {
    int tx = tid & 31;          // x fastest: consecutive tiles share halo cols
    int r  = tid >> 5;
    int ty = r & 15;
    bb = r >> 4;
    y0 = ty * 4;
    x0 = tx * 64;
}

__device__ __forceinline__ void stage_load(const float* __restrict__ depth,
                                           int tid, int t, float dreg[4]) {
    int bb, y0, x0;
    tile_coords(tid, bb, y0, x0);
    const float* Db = depth + (size_t)bb * HW;
#pragma unroll
    for (int i = 0; i < 4; ++i) {
        int idx = t + i * TPB;
        float v = 0.0f;
        if (idx < 12 * 72) {
            int ry = idx / 72, rx = idx - ry * 72;
            int gy = y0 + ry - 4, gx = x0 + rx - 4;
            if ((unsigned)gy < (unsigned)HH && (unsigned)gx < (unsigned)WW)
                v = Db[gy * WW + gx];
        }
        dreg[i] = v;
    }
}

__device__ __forceinline__ void stage_write(float (*sD)[72], int t,
                                            const float dreg[4]) {
#pragma unroll
    for (int i = 0; i < 4; ++i) {
        int idx = t + i * TPB;
        if (idx < 12 * 72) (&sD[0][0])[idx] = dreg[i];
    }
}

// one jy tap row of the accumulation; bit-exact chain order (jy outer, jx
// inner, k inner-most) — identical operand order to all passing rounds.
__device__ __forceinline__ void accum_row(const float (*sDt)[72],
                                          const float* sW,
                                          int py, int px, int gy,
                                          const float mx[5], int jy,
                                          float dist[25]) {
    const float* rp = &sDt[py + jy][px];   // runtime base, static offsets
    float row[5][9];                        // statically indexed only
#pragma unroll
    for (int r = 0; r < 5; ++r)
#pragma unroll
        for (int c = 0; c < 9; ++c)
            row[r][c] = rp[r * 72 + c];

    const float myy = ((unsigned)(gy + jy - 2) < (unsigned)HH) ? 1.0f : 0.0f;

#pragma unroll
    for (int jx = 0; jx < 5; ++jx) {
        const float wj = myy * mx[jx] * sW[jy * 5 + jx];  // exact *1.0/0.0
        const float Dq = row[2][jx + 2];
#pragma unroll
        for (int k = 0; k < 25; ++k) {
            if (k == 12) continue;
            const int ky = k / 5, kx = k % 5;
            const int nlin = ky * 9 + jx + kx, alin = 18 + jx + 2;
            // canonical operand order: |x-y|==|y-x| bit-exact, enables CSE
            const float diff = (nlin > alin) ? (row[ky][jx + kx] - Dq)
                                             : (Dq - row[ky][jx + kx]);
            dist[k] = fmaf(wj, fabsf(diff), dist[k]);
        }
    }
}

__device__ __forceinline__ void compute_tile(const float (*sDt)[72],
                                             const float* sW,
                                             const int* __restrict__ label,
                                             int tid, int t,
                                             int* __restrict__ out) {
    int bb, y0, x0;
    tile_coords(tid, bb, y0, x0);
    const int px = t & 63, py = t >> 6;
    const int gy = y0 + py, gx = x0 + px;
    const int* Lb = label + (size_t)bb * HW;

    // own label: coalesced global load issued early (latency hides under the
    // gate); k=12 has dist exactly +0.0 -> always the first top-k pick.
    const int labSelf = Lb[gy * WW + gx];
    int* const op = &out[(size_t)bb * HW + (size_t)gy * WW + gx];

    // anchor-OOB masks (exact 0/1): conv zero-pads jump in p-space
    float mx[5];
#pragma unroll
    for (int d = 0; d < 5; ++d)
        mx[d] = ((unsigned)(gx + d - 2) < (unsigned)WW) ? 1.0f : 0.0f;

    float dist[25];
#pragma unroll
    for (int k = 0; k < 25; ++k) dist[k] = 0.0f;
    // dist[12] (k-offset (0,0)) stays exactly +0.0: skipped everywhere.

    // ---- row-gated exact accumulation ----
#pragma clang loop unroll(disable)
    for (int jy = 0; jy < 5; ++jy) {
        accum_row(sDt, sW, py, px, gy, mx, jy, dist);
        float mn = 3.4e38f;
#pragma unroll
        for (int k = 0; k < 25; ++k) {
            if (k == 12) continue;
            mn = fminf(mn, dist[k]);
        }
        // prefix > 1 => final > 1 (monotone) => neighbor k votes NC.
        if (__all(mn > 1.0f)) {
            *op = labSelf;
            return;
        }
    }

    // ---- full path (needs genuinely-near neighbors; ~unreachable on real
    //      data but exact): dist[] already holds the complete chain. ----
    int labs[5];
    labs[0] = labSelf;
#pragma unroll
    for (int r = 1; r < 5; ++r) {
        float best = 3.4e38f;
        int bi = 0;
#pragma unroll
        for (int k = 0; k < 25; ++k) {
            if (k == 12) continue;
            if (dist[k] < best) { best = dist[k]; bi = k; }
        }
        int ky = (bi * 205) >> 10, kx = bi - ky * 5;   // bi/5, bi%5
        int ny = gy + ky - 2, nx = gx + kx - 2;
        // label unfold zero-pad: OOB neighbor label = 0
        int lv = ((unsigned)ny < (unsigned)HH && (unsigned)nx < (unsigned)WW)
                     ? Lb[ny * WW + nx] : 0;
        labs[r] = (best > 1.0f) ? NC : lv;
        if (r < 4) {
#pragma unroll
            for (int k = 0; k < 25; ++k) {
                if (k == 12) continue;
                if (k == bi) dist[k] = 3.4e38f;
            }
        }
    }

    // majority vote; argmax ties -> lowest class index
    int bestLab = 0, bestCnt = 0;
#pragma unroll
    for (int i = 0; i < 5; ++i) {
        const int li = labs[i];
        int c = 0;
#pragma unroll
        for (int j = 0; j < 5; ++j) c += (labs[j] == li) ? 1 : 0;
        if (li < NC && (c > bestCnt || (c == bestCnt && li < bestLab))) {
            bestCnt = c;
            bestLab = li;
        }
    }
    *op = bestLab;
}

__global__ __launch_bounds__(TPB) void knn_refine(
    const float* __restrict__ depth,
    const int*   __restrict__ label,
    const float* __restrict__ wker,
    int*         __restrict__ out)
{
    __shared__ float sD[2][12][72];
    __shared__ float sW[25];

    const int t    = threadIdx.x;
    const int tid0 = blockIdx.x * 2;          // 2 tiles per persistent block

    float dreg[4];

    // prologue: stage tile 0 into buffer 0
    stage_load(depth, tid0, t, dreg);
    if (t < 25) sW[t] = wker[t];
    stage_write(sD[0], t, dreg);
    __syncthreads();

    // tile 0: issue tile-1 loads FIRST (hidden under compute), then compute,
    // then park loads into buffer 1.
    stage_load(depth, tid0 + 1, t, dreg);
    compute_tile(sD[0], sW, label, tid0, t, out);
    stage_write(sD[1], t, dreg);
    __syncthreads();

    // tile 1
    compute_tile(sD[1], sW, label, tid0 + 1, t, out);
}

extern "C" void kernel_launch(void* const* d_in, const int* in_sizes, int n_in,
                              void* d_out, int out_size, void* d_ws, size_t ws_size,
                              hipStream_t stream) {
    const float* depth = (const float*)d_in[0];
    const int*   label = (const int*)d_in[1];
    const float* wker  = (const float*)d_in[2];
    int*         out   = (int*)d_out;

    knn_refine<<<dim3(2048), dim3(TPB), 0, stream>>>(depth, label, wker, out);
}

// Round 12
// 19.684 us; speedup vs baseline: 1.8169x; 1.1117x over previous
//
#include <hip/hip_runtime.h>

#define BB 8
#define HH 64
#define WW 2048
#define HW (HH * WW)
#define NC 20

// R12: barrier-free, LDS-free gate kernel. Grid (32,16,8), 256 thr, one 4x64
// tile per block, NO staging: each thread reads its 5x9 gate window straight
// from global (per-block footprint 2.3KB -> L1-resident; ~45x reuse per value).
//
// Gate (exact, monotone): dist[k]'s reference fma chain is j-ascending; rows
// jy < jyS := max(0, 2-gy) are exact fma(+0,*,*) no-ops (conv y-mask), so the
// chain prefix after row jyS equals the accumulated row-jyS sum. prefix > 1
// => final > 1 (fma with nonneg addend is monotone under RN) => neighbor
// votes NC => top-5 = {self, NC x4} => output own label. Waves failing the
// gate (P ~ 1e-5, incl. all borders) recompute the FULL exact chain from
// global (R10's HW-validated slow path, bit-identical).
//
// Ledger: R8 58.5 (persistent+prefetch) | R9 31.4 (row-0 gate, LDS) |
// R10 35.8 (top-border tail exposed) | R11 21.9 (per-row gate). R11 is
// ~4x above its issue floor with barrier-convoyed waves => remove sync.

__device__ __forceinline__ float gdepth(const float* __restrict__ Db, int y, int x) {
    // exact reference unfold zero-pad
    return ((unsigned)y < (unsigned)HH && (unsigned)x < (unsigned)WW)
               ? Db[y * WW + x] : 0.0f;
}

__global__ __launch_bounds__(256) void knn_refine(
    const float* __restrict__ depth,
    const int*   __restrict__ label,
    const float* __restrict__ wker,
    int*         __restrict__ out)
{
    const int t  = threadIdx.x;
    const int px = t & 63, py = t >> 6;
    const int b  = blockIdx.z;
    const int gy = blockIdx.y * 4 + py;            // wave-uniform
    const int gx = blockIdx.x * 64 + px;

    const float* Db = depth + (size_t)b * HW;
    const int*   Lb = label + (size_t)b * HW;

    // own label: coalesced, issued early; k=12 (dist exactly +0.0) is always
    // the first top-k pick (strict < scan, ties -> lower k = lax.top_k).
    const int labSelf = Lb[gy * WW + gx];
    int* const op = &out[(size_t)b * HW + (size_t)gy * WW + gx];

    const int  jyS  = (gy < 2) ? (2 - gy) : 0;     // first unmasked tap row
    const int  rtop = gy + jyS - 4;                // gate-window top image row
    const bool xInt = (blockIdx.x != 0) & (blockIdx.x != 31);  // wave-uniform

    // ---- 5x9 gate window from global (L1), exact zero-pad ----
    float win[5][9];
#pragma unroll
    for (int r = 0; r < 5; ++r) {
        const int ry = rtop + r;
        if ((unsigned)ry < (unsigned)HH) {          // wave-uniform branch
            const float* rowp = Db + ry * WW;
            if (xInt) {
#pragma unroll
                for (int c = 0; c < 9; ++c) win[r][c] = rowp[gx - 4 + c];
            } else {
#pragma unroll
                for (int c = 0; c < 9; ++c) {
                    const int x  = gx - 4 + c;
                    const int xc = min(max(x, 0), WW - 1);
                    const float v = rowp[xc];
                    win[r][c] = ((unsigned)x < (unsigned)WW) ? v : 0.0f;
                }
            }
        } else {
#pragma unroll
            for (int c = 0; c < 9; ++c) win[r][c] = 0.0f;
        }
    }

    // ---- gate row jyS: exact chain prefix (jx-ascending, k-inner) ----
    float dist[25];
#pragma unroll
    for (int k = 0; k < 25; ++k) dist[k] = 0.0f;
    // dist[12] (k-offset (0,0)) stays exactly +0.0: skipped everywhere.

#pragma unroll
    for (int jx = 0; jx < 5; ++jx) {
        float wj = wker[jyS * 5 + jx];              // uniform -> scalar load
        if (!xInt)                                  // conv x-mask, exact *1/0
            wj *= (((unsigned)(gx + jx - 2) < (unsigned)WW) ? 1.0f : 0.0f);
        const float Dq = win[2][jx + 2];
#pragma unroll
        for (int k = 0; k < 25; ++k) {
            if (k == 12) continue;
            const int ky = k / 5, kx = k % 5;
            const int nlin = ky * 9 + jx + kx, alin = 18 + jx + 2;
            // canonical operand order: |x-y|==|y-x| bit-exact, enables CSE
            const float diff = (nlin > alin) ? (win[ky][jx + kx] - Dq)
                                             : (Dq - win[ky][jx + kx]);
            dist[k] = fmaf(wj, fabsf(diff), dist[k]);
        }
    }

    float mn = 3.4e38f;
#pragma unroll
    for (int k = 0; k < 25; ++k) {
        if (k == 12) continue;
        mn = fminf(mn, dist[k]);
    }
    if (__all(mn > 1.0f)) {                         // prefix>1 => final>1
        *op = labSelf;
        return;
    }

    // ---- slow path (rare, wave-uniform): full exact recompute from global,
    //      j-ascending chain order, identical padding -> bit-identical dist --
    float mxm[5];
#pragma unroll
    for (int d = 0; d < 5; ++d)
        mxm[d] = ((unsigned)(gx + d - 2) < (unsigned)WW) ? 1.0f : 0.0f;

#pragma unroll
    for (int k = 0; k < 25; ++k) dist[k] = 0.0f;
#pragma clang loop unroll(disable)
    for (int jy = 0; jy < 5; ++jy) {
        float row[5][9];                            // statically indexed only
#pragma unroll
        for (int r = 0; r < 5; ++r)
#pragma unroll
            for (int c = 0; c < 9; ++c)
                row[r][c] = gdepth(Db, gy + jy + r - 4, gx + c - 4);
        const float myy = ((unsigned)(gy + jy - 2) < (unsigned)HH) ? 1.0f : 0.0f;
#pragma unroll
        for (int jx = 0; jx < 5; ++jx) {
            const float wj = myy * mxm[jx] * wker[jy * 5 + jx];
            const float Dq = row[2][jx + 2];
#pragma unroll
            for (int k = 0; k < 25; ++k) {
                if (k == 12) continue;
                const int ky = k / 5, kx = k % 5;
                const int nlin = ky * 9 + jx + kx, alin = 18 + jx + 2;
                const float diff = (nlin > alin) ? (row[ky][jx + kx] - Dq)
                                                 : (Dq - row[ky][jx + kx]);
                dist[k] = fmaf(wj, fabsf(diff), dist[k]);
            }
        }
    }

    // top-5 smallest (strict <, ties -> lower k = lax.top_k); round 0 = k=12
    int labs[5];
    labs[0] = labSelf;
#pragma unroll
    for (int r = 1; r < 5; ++r) {
        float best = 3.4e38f;
        int bi = 0;
#pragma unroll
        for (int k = 0; k < 25; ++k) {
            if (k == 12) continue;
            if (dist[k] < best) { best = dist[k]; bi = k; }
        }
        int ky = (bi * 205) >> 10, kx = bi - ky * 5;   // bi/5, bi%5
        int ny = gy + ky - 2, nx = gx + kx - 2;
        // label unfold zero-pad: OOB neighbor label = 0
        int lv = ((unsigned)ny < (unsigned)HH && (unsigned)nx < (unsigned)WW)
                     ? Lb[ny * WW + nx] : 0;
        labs[r] = (best > 1.0f) ? NC : lv;
        if (r < 4) {
#pragma unroll
            for (int k = 0; k < 25; ++k) {
                if (k == 12) continue;
                if (k == bi) dist[k] = 3.4e38f;
            }
        }
    }

    // majority vote; argmax ties -> lowest class index
    int bestLab = 0, bestCnt = 0;
#pragma unroll
    for (int i = 0; i < 5; ++i) {
        const int li = labs[i];
        int c = 0;
#pragma unroll
        for (int j = 0; j < 5; ++j) c += (labs[j] == li) ? 1 : 0;
        if (li < NC && (c > bestCnt || (c == bestCnt && li < bestLab))) {
            bestCnt = c;
            bestLab = li;
        }
    }
    *op = bestLab;
}

extern "C" void kernel_launch(void* const* d_in, const int* in_sizes, int n_in,
                              void* d_out, int out_size, void* d_ws, size_t ws_size,
                              hipStream_t stream) {
    const float* depth = (const float*)d_in[0];
    const int*   label = (const int*)d_in[1];
    const float* wker  = (const float*)d_in[2];
    int*         out   = (int*)d_out;

    knn_refine<<<dim3(32, 16, BB), dim3(256), 0, stream>>>(depth, label, wker, out);
}